// Round 1
// baseline (1410.217 us; speedup 1.0000x reference)
//
#include <hip/hip_runtime.h>
#include <hip/hip_bf16.h>
#include <cstdint>

#define DEVI __device__ __forceinline__

typedef __attribute__((ext_vector_type(8))) short short8;
typedef __attribute__((ext_vector_type(4))) float f32x4;
typedef unsigned int u32;
typedef unsigned short u16;

DEVI u16 f2bf(float f) {
  __hip_bfloat16 h = __float2bfloat16(f);
  return *reinterpret_cast<u16*>(&h);
}
DEVI float bf2f_lo(u32 u) { return __uint_as_float(u << 16); }
DEVI float bf2f_hi(u32 u) { return __uint_as_float(u & 0xffff0000u); }

// async global->LDS, 16B per lane. LDS dest must be wave-uniform base + lane*16.
DEVI void async_cp16(const __hip_bfloat16* g, __hip_bfloat16* l) {
  __builtin_amdgcn_global_load_lds(
      (const __attribute__((address_space(1))) u32*)(uintptr_t)g,
      (__attribute__((address_space(3))) u32*)(uintptr_t)l, 16, 0, 0);
}

// ---------------------------------------------------------------------------
// Generic TN GEMM: Z[n][m] = alpha * (sum_k A[m][k]*B[n][k] + bias) + resid
// A: M x K (K contiguous, leading dim lda), B: N x K (ldb). Both bf16.
// Z layout: addr = n*ldz + m (M contiguous). Tile 128x128, BK=32, 4 waves 2x2.
// BIAS_MODE: 0 none, 1 per-M (indexed by m), 2 per-N (indexed by n).
// ---------------------------------------------------------------------------
template<int BIAS_MODE, bool RESID, bool OUT_BF16>
__global__ __launch_bounds__(256) void gemm_tn(
    const __hip_bfloat16* __restrict__ A, int lda, size_t sA,
    const __hip_bfloat16* __restrict__ B, int ldb, size_t sB,
    void* __restrict__ Zv, int ldz, size_t sZ,
    const float* __restrict__ bias,
    const float* __restrict__ resid, size_t sR,
    float alpha, int K)
{
  __shared__ __hip_bfloat16 lsA[128 * 32];
  __shared__ __hip_bfloat16 lsB[128 * 32];
  const int t    = threadIdx.x;
  const int bz   = blockIdx.z;
  const int n0   = blockIdx.x * 128;
  const int m0   = blockIdx.y * 128;
  const __hip_bfloat16* Ab = A + (size_t)bz * sA;
  const __hip_bfloat16* Bb = B + (size_t)bz * sB;

  const int lane = t & 63;
  const int quad = lane >> 4;
  const int l16  = lane & 15;
  const int wave = t >> 6;
  const int wm   = (wave >> 1) * 64;
  const int wn   = (wave & 1) * 64;

  // staging: 128 rows x 32 bf16 (64B) per tile = 512 x 16B chunks; 2 per thread
  const int rowc = t >> 2;
  const int kc   = (t & 3) * 8;
  const __hip_bfloat16* ga0 = Ab + (size_t)(m0 + rowc) * lda + kc;
  const __hip_bfloat16* ga1 = Ab + (size_t)(m0 + rowc + 64) * lda + kc;
  const __hip_bfloat16* gb0 = Bb + (size_t)(n0 + rowc) * ldb + kc;
  const __hip_bfloat16* gb1 = Bb + (size_t)(n0 + rowc + 64) * ldb + kc;
  __hip_bfloat16* la0 = lsA + t * 8;
  __hip_bfloat16* la1 = lsA + 2048 + t * 8;
  __hip_bfloat16* lb0 = lsB + t * 8;
  __hip_bfloat16* lb1 = lsB + 2048 + t * 8;

  f32x4 acc[4][4] = {};

  for (int k0 = 0; k0 < K; k0 += 32) {
    __syncthreads();            // protect LDS from previous iteration's readers
    async_cp16(ga0, la0);
    async_cp16(ga1, la1);
    async_cp16(gb0, lb0);
    async_cp16(gb1, lb1);
    ga0 += 32; ga1 += 32; gb0 += 32; gb1 += 32;
    __syncthreads();            // compiler emits vmcnt(0) drain before barrier

    short8 af[4], bf[4];
#pragma unroll
    for (int i = 0; i < 4; ++i)
      af[i] = *(const short8*)(lsA + (wm + i * 16 + l16) * 32 + quad * 8);
#pragma unroll
    for (int j = 0; j < 4; ++j)
      bf[j] = *(const short8*)(lsB + (wn + j * 16 + l16) * 32 + quad * 8);
#pragma unroll
    for (int i = 0; i < 4; ++i)
#pragma unroll
      for (int j = 0; j < 4; ++j)
        acc[i][j] = __builtin_amdgcn_mfma_f32_16x16x32_bf16(af[i], bf[j], acc[i][j], 0, 0, 0);
  }

  // epilogue: C frag = col(lane&15)=n, rows quad*4+r = m (4 consecutive m)
#pragma unroll
  for (int i = 0; i < 4; ++i) {
#pragma unroll
    for (int j = 0; j < 4; ++j) {
      const int m = m0 + wm + i * 16 + quad * 4;
      const int n = n0 + wn + j * 16 + l16;
      f32x4 v = acc[i][j];
      if (BIAS_MODE == 1) v += *(const f32x4*)(bias + m);
      else if (BIAS_MODE == 2) v += bias[n];
      v *= alpha;
      const size_t zoff = (size_t)n * ldz + m;
      if (RESID) v += *(const f32x4*)(resid + (size_t)bz * sR + zoff);
      if (OUT_BF16) {
        union { u16 s[4]; uint2 q; } pk;
        pk.s[0] = f2bf(v[0]); pk.s[1] = f2bf(v[1]);
        pk.s[2] = f2bf(v[2]); pk.s[3] = f2bf(v[3]);
        *(uint2*)((__hip_bfloat16*)Zv + (size_t)bz * sZ + zoff) = pk.q;
      } else {
        *(f32x4*)((float*)Zv + (size_t)bz * sZ + zoff) = v;
      }
    }
  }
}

// ---------------------------------------------------------------------------
// GroupNorm stats: one block per (b, group). 16 channels x 4096 = 65536 floats,
// contiguous in x. Writes (mu, rstd).
// ---------------------------------------------------------------------------
__global__ __launch_bounds__(256) void gn_stats(const float* __restrict__ x,
                                                float2* __restrict__ stats) {
  const int bg = blockIdx.x;
  const f32x4* p = (const f32x4*)(x + (size_t)bg * 65536);
  float s = 0.f, s2 = 0.f;
  for (int i = threadIdx.x; i < 16384; i += 256) {
    f32x4 v = p[i];
    s  += v[0] + v[1] + v[2] + v[3];
    s2 += v[0]*v[0] + v[1]*v[1] + v[2]*v[2] + v[3]*v[3];
  }
  for (int o = 32; o > 0; o >>= 1) { s += __shfl_down(s, o); s2 += __shfl_down(s2, o); }
  __shared__ float ws[4], ws2[4];
  const int wave = threadIdx.x >> 6;
  if ((threadIdx.x & 63) == 0) { ws[wave] = s; ws2[wave] = s2; }
  __syncthreads();
  if (threadIdx.x == 0) {
    float S  = ws[0] + ws[1] + ws[2] + ws[3];
    float S2 = ws2[0] + ws2[1] + ws2[2] + ws2[3];
    float mu = S * (1.f / 65536.f);
    float var = S2 * (1.f / 65536.f) - mu * mu;
    stats[bg] = make_float2(mu, rsqrtf(var + 1e-6f));
  }
}

// ---------------------------------------------------------------------------
// GroupNorm apply + transpose: x[b][c][n] fp32 -> r_t[b][n][c] bf16.
// Block per (b, 64-wide n tile); loop 8 chunks of 64 channels via LDS.
// ---------------------------------------------------------------------------
__global__ __launch_bounds__(256) void gn_apply(const float* __restrict__ x,
                                                const float2* __restrict__ stats,
                                                const float* __restrict__ gamma,
                                                const float* __restrict__ beta,
                                                __hip_bfloat16* __restrict__ rt) {
  const int b = blockIdx.y, n0 = blockIdx.x * 64;
  __shared__ float tile[64][65];
  const int t  = threadIdx.x;
  const int cl = t >> 2;          // 0..63 local channel (read phase)
  const int q4 = (t & 3) * 4;     // n sub-offset (read phase)
  for (int cc = 0; cc < 8; ++cc) {
    const int c = cc * 64 + cl;
    const float2 ms = stats[b * 32 + (c >> 4)];
    const float ga = gamma[c] * ms.y;
    const float be = beta[c] - ms.x * ga;
    const float* src = x + ((size_t)b * 512 + c) * 4096 + n0;
#pragma unroll
    for (int p = 0; p < 4; ++p) {
      f32x4 v = *(const f32x4*)(src + q4 + p * 16);
      tile[cl][q4 + p * 16 + 0] = fmaf(v[0], ga, be);
      tile[cl][q4 + p * 16 + 1] = fmaf(v[1], ga, be);
      tile[cl][q4 + p * 16 + 2] = fmaf(v[2], ga, be);
      tile[cl][q4 + p * 16 + 3] = fmaf(v[3], ga, be);
    }
    __syncthreads();
    const int nw = t >> 2;        // 0..63 local n (write phase)
    const int cw = (t & 3) * 16;  // channel sub-offset
    union { u16 s[16]; uint4 q[2]; } pk;
#pragma unroll
    for (int j = 0; j < 16; ++j) pk.s[j] = f2bf(tile[cw + j][nw]);
    __hip_bfloat16* dst = rt + ((size_t)b * 4096 + n0 + nw) * 512 + cc * 64 + cw;
    *(uint4*)dst = pk.q[0];
    *((uint4*)dst + 1) = pk.q[1];
    __syncthreads();
  }
}

// ---------------------------------------------------------------------------
// Row softmax, in place, bf16 storage / fp32 math. One block per 4096-row.
// ---------------------------------------------------------------------------
__global__ __launch_bounds__(256) void softmax_rows(__hip_bfloat16* __restrict__ a) {
  __hip_bfloat16* p = a + (size_t)blockIdx.x * 4096;
  const int t = threadIdx.x;
  uint4 r0 = *(uint4*)(p + t * 16);
  uint4 r1 = *(uint4*)(p + t * 16 + 8);
  float v[16];
  v[0]=bf2f_lo(r0.x); v[1]=bf2f_hi(r0.x); v[2]=bf2f_lo(r0.y); v[3]=bf2f_hi(r0.y);
  v[4]=bf2f_lo(r0.z); v[5]=bf2f_hi(r0.z); v[6]=bf2f_lo(r0.w); v[7]=bf2f_hi(r0.w);
  v[8]=bf2f_lo(r1.x); v[9]=bf2f_hi(r1.x); v[10]=bf2f_lo(r1.y); v[11]=bf2f_hi(r1.y);
  v[12]=bf2f_lo(r1.z); v[13]=bf2f_hi(r1.z); v[14]=bf2f_lo(r1.w); v[15]=bf2f_hi(r1.w);

  __shared__ float red[4];
  const int wave = t >> 6, lane = t & 63;

  float mx = v[0];
#pragma unroll
  for (int i = 1; i < 16; ++i) mx = fmaxf(mx, v[i]);
  for (int o = 32; o > 0; o >>= 1) mx = fmaxf(mx, __shfl_down(mx, o));
  if (lane == 0) red[wave] = mx;
  __syncthreads();
  mx = fmaxf(fmaxf(red[0], red[1]), fmaxf(red[2], red[3]));
  __syncthreads();

  float sum = 0.f;
#pragma unroll
  for (int i = 0; i < 16; ++i) { v[i] = __expf(v[i] - mx); sum += v[i]; }
  for (int o = 32; o > 0; o >>= 1) sum += __shfl_down(sum, o);
  if (lane == 0) red[wave] = sum;
  __syncthreads();
  sum = red[0] + red[1] + red[2] + red[3];
  const float inv = 1.f / sum;

  union { u16 s[16]; uint4 q[2]; } pk;
#pragma unroll
  for (int i = 0; i < 16; ++i) pk.s[i] = f2bf(v[i] * inv);
  *(uint4*)(p + t * 16) = pk.q[0];
  *(uint4*)(p + t * 16 + 8) = pk.q[1];
}

// fp32 -> bf16 cast (weights)
__global__ __launch_bounds__(256) void cvt_bf16(const float* __restrict__ s,
                                                __hip_bfloat16* __restrict__ d, int n) {
  const int i = (blockIdx.x * 256 + threadIdx.x) * 4;
  if (i < n) {
    f32x4 v = *(const f32x4*)(s + i);
    union { u16 s4[4]; uint2 q; } pk;
    pk.s4[0] = f2bf(v[0]); pk.s4[1] = f2bf(v[1]);
    pk.s4[2] = f2bf(v[2]); pk.s4[3] = f2bf(v[3]);
    *(uint2*)(d + i) = pk.q;
  }
}

// ---------------------------------------------------------------------------
extern "C" void kernel_launch(void* const* d_in, const int* in_sizes, int n_in,
                              void* d_out, int out_size, void* d_ws, size_t ws_size,
                              hipStream_t stream) {
  const float* x     = (const float*)d_in[0];
  const float* gamma = (const float*)d_in[1];
  const float* beta  = (const float*)d_in[2];
  const float* q_w   = (const float*)d_in[3];
  const float* q_b   = (const float*)d_in[4];
  const float* k_w   = (const float*)d_in[5];
  const float* k_b   = (const float*)d_in[6];
  const float* p_w   = (const float*)d_in[7];
  const float* p_b   = (const float*)d_in[8];
  float* out = (float*)d_out;

  constexpr int B = 8, C = 512, N = 4096;
  constexpr size_t NC = (size_t)N * C;   // per-batch elems of [n][c] / [c][n]

  char* ws = (char*)d_ws;
  size_t off = 0;
  auto alloc = [&](size_t bytes) {
    void* p = ws + off;
    off += (bytes + 255) & ~(size_t)255;
    return p;
  };

  __hip_bfloat16* wq = (__hip_bfloat16*)alloc((size_t)C * C * 2);
  __hip_bfloat16* wk = (__hip_bfloat16*)alloc((size_t)C * C * 2);
  __hip_bfloat16* wp = (__hip_bfloat16*)alloc((size_t)C * C * 2);
  float2* stats      = (float2*)alloc((size_t)B * 32 * sizeof(float2));
  __hip_bfloat16* rt = (__hip_bfloat16*)alloc(B * NC * 2);  // r_t[b][n][c]
  __hip_bfloat16* qt = (__hip_bfloat16*)alloc(B * NC * 2);  // q_t[b][n][c] (scaled)
  __hip_bfloat16* kt = (__hip_bfloat16*)alloc(B * NC * 2);  // k_t[b][m][c]
  __hip_bfloat16* kc = (__hip_bfloat16*)alloc(B * NC * 2);  // k_c[b][c][m]
  __hip_bfloat16* ot = (__hip_bfloat16*)alloc(B * NC * 2);  // O_t[b][n][c]
  const size_t full_need = off + (size_t)B * N * N * 2;
  const bool full = full_need <= ws_size;
  __hip_bfloat16* attn =
      (__hip_bfloat16*)alloc(full ? (size_t)B * N * N * 2 : (size_t)N * N * 2);

  const dim3 blk(256);
  const float scale = 0.044194173824159216f;  // 512^-0.5, folded into q

  cvt_bf16<<<dim3(C * C / 1024), blk, 0, stream>>>(q_w, wq, C * C);
  cvt_bf16<<<dim3(C * C / 1024), blk, 0, stream>>>(k_w, wk, C * C);
  cvt_bf16<<<dim3(C * C / 1024), blk, 0, stream>>>(p_w, wp, C * C);

  gn_stats<<<dim3(B * 32), blk, 0, stream>>>(x, stats);
  gn_apply<<<dim3(64, B), blk, 0, stream>>>(x, stats, gamma, beta, rt);

  // q_t[n][o] = scale*(Wq . r + qb) : M'=o(512), N'=n(4096)
  gemm_tn<1, false, true><<<dim3(32, 4, B), blk, 0, stream>>>(
      wq, C, 0, rt, C, NC, qt, C, NC, q_b, nullptr, 0, scale, C);
  // k_t[m][o] : same shape
  gemm_tn<1, false, true><<<dim3(32, 4, B), blk, 0, stream>>>(
      wk, C, 0, rt, C, NC, kt, C, NC, k_b, nullptr, 0, 1.f, C);
  // k_c[o][m] : M'=m(4096), N'=o(512)
  gemm_tn<2, false, true><<<dim3(4, 32, B), blk, 0, stream>>>(
      rt, C, NC, wk, C, 0, kc, N, NC, k_b, nullptr, 0, 1.f, C);

  if (full) {
    // scores[n][m] = sum_c k_t[m][c]*q_t[n][c]
    gemm_tn<0, false, true><<<dim3(32, 32, B), blk, 0, stream>>>(
        kt, C, NC, qt, C, NC, attn, N, (size_t)N * N, nullptr, nullptr, 0, 1.f, C);
    softmax_rows<<<dim3(B * 4096), blk, 0, stream>>>(attn);
    // O_t[n][c] = sum_m k_c[c][m]*attn[n][m]
    gemm_tn<0, false, true><<<dim3(32, 4, B), blk, 0, stream>>>(
        kc, N, NC, attn, N, (size_t)N * N, ot, C, NC, nullptr, nullptr, 0, 1.f, N);
  } else {
    for (int b = 0; b < B; ++b) {
      gemm_tn<0, false, true><<<dim3(32, 32, 1), blk, 0, stream>>>(
          kt + b * NC, C, 0, qt + b * NC, C, 0, attn, N, 0, nullptr, nullptr, 0, 1.f, C);
      softmax_rows<<<dim3(4096), blk, 0, stream>>>(attn);
      gemm_tn<0, false, true><<<dim3(32, 4, 1), blk, 0, stream>>>(
          kc + b * NC, N, 0, attn, N, 0, ot + b * NC, C, 0, nullptr, nullptr, 0, 1.f, N);
    }
  }

  // out[o][n] = Wp . O + pb + x : M'=n(4096), N'=o(512), fp32 + residual
  gemm_tn<2, true, false><<<dim3(4, 32, B), blk, 0, stream>>>(
      ot, C, NC, wp, C, 0, out, N, NC, p_b, x, NC, 1.f, C);
}